// Round 26
// baseline (119.472 us; speedup 1.0000x reference)
//
#include <hip/hip_runtime.h>
#include <hip/hip_bf16.h>
#include <stdint.h>

// B=8, C=256, H=W=64 (N=4096), T=512
// out0 = F_s + (softmax(Fs_t @ Ft^T / sqrt(T)) @ Ft) in [B][C][N] layout, fp32
// out1 = P^T @ Fs_t   [B][T][C] fp32

typedef __attribute__((ext_vector_type(8))) short short8v;   // 8 bf16
typedef __attribute__((ext_vector_type(4))) float float4v;

#define MFMA16(a, b, c) __builtin_amdgcn_mfma_f32_16x16x32_bf16(a, b, c, 0, 0, 0)
#define SCALE 0.04419417382415922f  // 1/sqrt(512)

static __device__ __forceinline__ unsigned short f2bf(float f) {
  union { float f; uint32_t u; } v; v.f = f;
  uint32_t r = v.u + 0x7fffu + ((v.u >> 16) & 1u);   // RNE
  return (unsigned short)(r >> 16);
}
static __device__ __forceinline__ float bf2f(unsigned short u) {
  union { uint32_t u; float f; } v; v.u = (uint32_t)u << 16;
  return v.f;
}

// async global->LDS, 16B per lane; LDS dest is wave-uniform base + lane*16
static __device__ __forceinline__ void gload16(const void* g, void* l) {
  __builtin_amdgcn_global_load_lds(
      (const __attribute__((address_space(1))) void*)g,
      (__attribute__((address_space(3))) void*)l, 16, 0, 0);
}

// ---------- cast + transpose (unchanged) ----------
__global__ __launch_bounds__(256) void k_cast_transpose(
    const float* __restrict__ src, unsigned short* __restrict__ dstC,
    unsigned short* __restrict__ dstT, int R, int Cd) {
  __shared__ unsigned short tile[32][33];
  const size_t zoff = (size_t)blockIdx.z * R * Cd;
  const float* s = src + zoff;
  unsigned short* dc = dstC + zoff;
  unsigned short* dt = dstT + zoff;
  const int c0 = blockIdx.x * 32, r0 = blockIdx.y * 32;
  const int tid = threadIdx.x;
  const int r = tid >> 3, c4 = (tid & 7) * 4;

  float4 v = *(const float4*)&s[(size_t)(r0 + r) * Cd + c0 + c4];
  ushort4 bq;
  bq.x = f2bf(v.x); bq.y = f2bf(v.y); bq.z = f2bf(v.z); bq.w = f2bf(v.w);
  *(ushort4*)&dc[(size_t)(r0 + r) * Cd + c0 + c4] = bq;
  tile[r][c4 + 0] = bq.x; tile[r][c4 + 1] = bq.y;
  tile[r][c4 + 2] = bq.z; tile[r][c4 + 3] = bq.w;
  __syncthreads();
  ushort4 o;
  o.x = tile[c4 + 0][r]; o.y = tile[c4 + 1][r];
  o.z = tile[c4 + 2][r]; o.w = tile[c4 + 3][r];
  *(ushort4*)&dt[(size_t)(c0 + r) * R + r0 + c4] = o;
}

// ---------- k_attn v-stream (r26): no-max streaming softmax, 3 blocks/CU ----
// Numerics: logits*SCALE ~ N(0,0.7^2), |max| ~ 3.5 << 88 -> exp cannot
// overflow; max-subtraction dropped. Per 32-t chunk: QK^T -> exp -> l +=
// -> unnormalized E written to PT + PV-accumulated. out0 normalized by
// 1/l in-register; out1 normalized in k_ptq via invl[] (folded into A-frags).
// Live state ~140 VGPR (oacc 64 + aQ 32 + chunk 8) -> fits (256,3).
// grid 512 (64 nb x 8 b), 4 waves, each owns 16 q, full T and C.
// LDS 53,248 B (<= 160K/3): [0,49152) 3 stage bufs x 16 KB (stage s -> buf
// s%3; even s = K chunk, odd s = VT chunk); [49152,53248) Ps 4 waves x 1 KB.
// Sync per sub-iteration (r21-proven order): vmcnt(4) [2 stages = 8 loads
// outstanding -> retires stage s] -> barrier -> issue s+2 -> compute ->
// lgkmcnt(0). Tail: s=31 -> vmcnt(0).
__global__ __launch_bounds__(256, 3) void k_attn(
    const unsigned short* __restrict__ Qg, const unsigned short* __restrict__ Kg,
    const unsigned short* __restrict__ VTg, const unsigned short* __restrict__ QTg,
    float* __restrict__ out0, unsigned short* __restrict__ PTg,
    float* __restrict__ invlg) {
  __shared__ char smem[53248];

  const int tid = threadIdx.x;
  const int wave = tid >> 6, lane = tid & 63;
  const int l16 = lane & 15, lhi = lane >> 4;
  const int b = blockIdx.x & 7, nb = blockIdx.x >> 3;
  const int n0w = nb * 64 + wave * 16;       // this wave's 16 q-rows
  const int cx = (l16 & 7) << 4;             // swizzle for 512B rows (K)
  const int cx2 = (l16 & 3) << 4;            // swizzle for 64B rows (VT, Ps)

  const unsigned short* Qb = Qg + (size_t)b * 4096 * 256;
  const char* Kb = (const char*)(Kg + (size_t)b * 512 * 256);
  const char* VTb = (const char*)(VTg + (size_t)b * 256 * 512);
  char* Ps = smem + 49152 + wave * 1024;     // wave-private [16q][32t]

  // K chunk i = [32t][256c] 16 KB contiguous -> buf (2i)%3
#define STAGE_K(i_) do {                                                    \
    const char* src_ = Kb + (i_) * 16384;                                   \
    char* dst_ = smem + ((2 * (i_)) % 3) * 16384;                           \
    _Pragma("unroll")                                                       \
    for (int u = 0; u < 4; u++) {                                           \
      const int off = (tid + u * 256) * 16;                                 \
      gload16(src_ + (off ^ (((off >> 9) & 7) << 4)), dst_ + off);          \
    } } while (0)

  // VT chunk i = [256c][32t] 16 KB (64 B rows) -> buf (2i+1)%3
#define STAGE_V(i_) do {                                                    \
    char* dst_ = smem + ((2 * (i_) + 1) % 3) * 16384;                       \
    _Pragma("unroll")                                                       \
    for (int u = 0; u < 4; u++) {                                           \
      const int off = (tid + u * 256) * 16;                                 \
      const int r_ = off >> 6, ic_ = off & 63;                              \
      gload16(VTb + (size_t)r_ * 1024 + (i_) * 64 + (ic_ ^ ((r_ & 3) << 4)), \
              dst_ + off);                                                  \
    } } while (0)

  // ---- Q A-frags (rows = q = l16) ----
  short8v aQ[8];
#pragma unroll
  for (int kc = 0; kc < 8; kc++)
    aQ[kc] = *(const short8v*)(Qb + (size_t)(n0w + l16) * 256 + kc * 32 + lhi * 8);

  float4v oacc[16];
#pragma unroll
  for (int ct = 0; ct < 16; ct++) oacc[ct] = (float4v)0.f;
  float lrun[4] = {0.f, 0.f, 0.f, 0.f};

  unsigned short* PTb = PTg + (size_t)b * 512 * 4096;

  STAGE_K(0); STAGE_V(0);                    // 8 loads outstanding
#pragma unroll
  for (int i = 0; i < 16; i++) {
    // ---- even sub-iter (s=2i): K_i ready ----
    asm volatile("s_waitcnt vmcnt(4)" ::: "memory");   // K_i landed (mine)
    __builtin_amdgcn_s_barrier();                      // all waves' K_i landed
    if (i < 15) STAGE_K(i + 1);
    float4v s0 = (float4v)0.f, s1 = (float4v)0.f;
    {
      const char* kb = smem + ((2 * i) % 3) * 16384;
      const char* rb0 = kb + l16 * 512;                // t-tile 0 rows
      const char* rb1 = kb + (16 + l16) * 512;         // t-tile 1 rows
#pragma unroll
      for (int kc = 0; kc < 8; kc++) {
        short8v bf0 = *(const short8v*)(rb0 + ((kc * 64 + lhi * 16) ^ cx));
        s0 = MFMA16(aQ[kc], bf0, s0);
        short8v bf1 = *(const short8v*)(rb1 + ((kc * 64 + lhi * 16) ^ cx));
        s1 = MFMA16(aQ[kc], bf1, s1);
      }
    }
    asm volatile("s_waitcnt lgkmcnt(0)" ::: "memory");

    // ---- odd sub-iter (s=2i+1): V_i ready ----
    if (i < 15) asm volatile("s_waitcnt vmcnt(4)" ::: "memory");
    else        asm volatile("s_waitcnt vmcnt(0)" ::: "memory");
    __builtin_amdgcn_s_barrier();
    if (i < 15) STAGE_V(i + 1);
    // exp + l accumulate + Ps write (unnormalized E, bf16), wave-private
#pragma unroll
    for (int r = 0; r < 4; r++) {
      const int q = lhi * 4 + r;
      float p0 = __expf(s0[r] * SCALE);
      float p1 = __expf(s1[r] * SCALE);
      lrun[r] += p0 + p1;
      *(unsigned short*)(Ps + ((q * 64 + l16 * 2) ^ ((q & 3) << 4))) = f2bf(p0);
      *(unsigned short*)(Ps + ((q * 64 + (16 + l16) * 2) ^ ((q & 3) << 4))) = f2bf(p1);
    }
    asm volatile("s_waitcnt lgkmcnt(0)" ::: "memory");  // Ps visible (same wave)
    // PV: D[c][q] += VT_chunk @ E_chunk (K=32)
    {
      short8v pb = *(const short8v*)(Ps + ((l16 * 64 + lhi * 16) ^ cx2));
      const char* vb = smem + ((2 * i + 1) % 3) * 16384;
#pragma unroll
      for (int ct = 0; ct < 16; ct++) {
        const char* rb = vb + (ct * 16 + l16) * 64;    // row&3 == l16&3
        short8v av = *(const short8v*)(rb + ((lhi * 16) ^ cx2));
        oacc[ct] = MFMA16(av, pb, oacc[ct]);
      }
    }
    // PT write for chunk i (unnormalized): t2 = lane&31, q-cols half*8..+8
    {
      const int t2 = lane & 31, half = lane >> 5;
      unsigned short tmp[8];
#pragma unroll
      for (int j = 0; j < 8; j++) {
        const int q = half * 8 + j;
        tmp[j] = *(const unsigned short*)(Ps + ((q * 64 + t2 * 2) ^ ((q & 3) << 4)));
      }
      *(int4*)(PTb + (size_t)(32 * i + t2) * 4096 + n0w + half * 8) = *(int4*)tmp;
    }
    asm volatile("s_waitcnt lgkmcnt(0)" ::: "memory");
  }

  // ---- epilogue: l reduce -> invl; scale oacc; write out0 + invl ----
#pragma unroll
  for (int r = 0; r < 4; r++) {
    float l = lrun[r];
    l += __shfl_xor(l, 1); l += __shfl_xor(l, 2);
    l += __shfl_xor(l, 4); l += __shfl_xor(l, 8);
    lrun[r] = 1.0f / l;                      // invl for q = lhi*4 + r
  }
  // myinv for q = l16 (oacc col): gather via shfl from subgroup (l16>>2)
  const int srcl = (l16 >> 2) << 4;
  float va = __shfl(lrun[0], srcl), vb2 = __shfl(lrun[1], srcl);
  float vc = __shfl(lrun[2], srcl), vd = __shfl(lrun[3], srcl);
  const int rs = l16 & 3;
  float myinv = rs == 0 ? va : (rs == 1 ? vb2 : (rs == 2 ? vc : vd));
  if (lane < 16) invlg[(size_t)b * 4096 + n0w + lane] = myinv;

  const unsigned short* QTb = QTg + (size_t)b * 256 * 4096;
  float* o0 = out0 + (size_t)b * 256 * 4096;
#pragma unroll
  for (int ct = 0; ct < 16; ct++)
#pragma unroll
    for (int r = 0; r < 4; r++) {
      const int cgl = ct * 16 + lhi * 4 + r;
      const size_t off = (size_t)cgl * 4096 + n0w + l16;
      o0[off] = oacc[ct][r] * myinv + bf2f(QTb[off]);
    }
#undef STAGE_K
#undef STAGE_V
}

// ---------- k_ptq v8: split-K 8, bf16 partials, invl-scaled A-frags ----------
// PT now holds UNNORMALIZED E; normalize by invl[n] folded into the A-frag
// (8 unpack-mul-pack per frag; k_ptq VALUBusy was 2.4% -> headroom).
__global__ __launch_bounds__(256, 2) void k_ptq(
    const unsigned short* __restrict__ PTg, const unsigned short* __restrict__ QTg,
    const float* __restrict__ invlg, unsigned short* __restrict__ part) {
  __shared__ char smem[65536];

  const int tid = threadIdx.x;
  const int wave = tid >> 6, lane = tid & 63;
  const int l16 = lane & 15, lhi = lane >> 4;
  const int bid = blockIdx.x;
  const int t0 = (bid >> 6) * 64;
  const int grp = bid & 63;
  const int b = grp & 7, ksl = grp >> 3;
  const int cx = (l16 & 7) << 4;

  const unsigned short* PTrow =
      PTg + ((size_t)(b * 512 + t0 + wave * 16 + l16)) * 4096 + ksl * 512 + lhi * 8;
  const char* QTb = (const char*)(QTg + (size_t)b * 256 * 4096 + ksl * 512);
  const float* ivb = invlg + (size_t)b * 4096 + ksl * 512 + lhi * 8;

#define STAGE_Q(c_, buf_) do {                                              \
    _Pragma("unroll")                                                       \
    for (int u = 0; u < 8; u++) {                                           \
      const int off = (tid + u * 256) * 16;                                 \
      const int r_ = off >> 7, ic_ = off & 127;                             \
      gload16(QTb + (size_t)r_ * 8192 + (c_) * 128 + (ic_ ^ ((r_ & 7) << 4)), \
              smem + (buf_) * 32768 + off);                                 \
    } } while (0)

  float4v acc[16];
#pragma unroll
  for (int ct = 0; ct < 16; ct++) acc[ct] = (float4v)0.f;

  STAGE_Q(0, 0);
  __syncthreads();
#pragma unroll
  for (int c = 0; c < 8; c++) {
    const int buf = c & 1;
    short8v pa0 = *(const short8v*)(PTrow + c * 64);
    short8v pa1 = *(const short8v*)(PTrow + c * 64 + 32);
    // normalize A-frags by invl[n] (fp32 mul, repack bf16)
    {
      float4 iv0 = *(const float4*)(ivb + c * 64);
      float4 iv1 = *(const float4*)(ivb + c * 64 + 4);
      float4 iv2 = *(const float4*)(ivb + c * 64 + 32);
      float4 iv3 = *(const float4*)(ivb + c * 64 + 36);
      const float f0[8] = {iv0.x, iv0.y, iv0.z, iv0.w, iv1.x, iv1.y, iv1.z, iv1.w};
      const float f1[8] = {iv2.x, iv2.y, iv2.z, iv2.w, iv3.x, iv3.y, iv3.z, iv3.w};
#pragma unroll
      for (int j = 0; j < 8; j++) {
        pa0[j] = (short)f2bf(bf2f((unsigned short)pa0[j]) * f0[j]);
        pa1[j] = (short)f2bf(bf2f((unsigned short)pa1[j]) * f1[j]);
      }
    }
    if (c < 7) STAGE_Q(c + 1, buf ^ 1);
#pragma unroll
    for (int ct = 0; ct < 16; ct++) {
      const int row = ct * 16 + l16;             // row&7 == l16&7
      const char* rb = smem + buf * 32768 + row * 128;
      short8v b0 = *(const short8v*)(rb + ((lhi * 16) ^ cx));
      acc[ct] = MFMA16(pa0, b0, acc[ct]);
      short8v b1 = *(const short8v*)(rb + ((64 + lhi * 16) ^ cx));
      acc[ct] = MFMA16(pa1, b1, acc[ct]);
    }
    __syncthreads();
  }

  // partial[ksl][b][t][c] bf16 stores (l16 -> 16 contiguous c)
  unsigned short* pout = part + (((size_t)ksl * 8 + b) * 512 + t0 + wave * 16) * 256;
#pragma unroll
  for (int ct = 0; ct < 16; ct++)
#pragma unroll
    for (int r = 0; r < 4; r++)
      pout[(lhi * 4 + r) * 256 + ct * 16 + l16] = f2bf(acc[ct][r]);
#undef STAGE_Q
}

// ---------- k_red v3 (unchanged): out1 = sum over 8 bf16 partials ----------
__global__ __launch_bounds__(256) void k_red(
    const unsigned short* __restrict__ part, float* __restrict__ out1) {
  const size_t g = (size_t)(blockIdx.x * 256 + threadIdx.x) * 8;
  float s[8];
#pragma unroll
  for (int j = 0; j < 8; j++) s[j] = 0.f;
#pragma unroll
  for (int ksl = 0; ksl < 8; ksl++) {
    short8v v = *(const short8v*)(part + (size_t)ksl * 1048576 + g);
#pragma unroll
    for (int j = 0; j < 8; j++) s[j] += bf2f((unsigned short)v[j]);
  }
  float4 o0 = {s[0], s[1], s[2], s[3]};
  float4 o1 = {s[4], s[5], s[6], s[7]};
  *(float4*)(out1 + g) = o0;
  *(float4*)(out1 + g + 4) = o1;
}

extern "C" void kernel_launch(void* const* d_in, const int* in_sizes, int n_in,
                              void* d_out, int out_size, void* d_ws, size_t ws_size,
                              hipStream_t stream) {
  const float* Fs = (const float*)d_in[0];   // [8][256][4096]
  const float* Ft = (const float*)d_in[1];   // [8][512][256]
  float* out0 = (float*)d_out;               // [8][256][4096]
  float* out1 = out0 + (size_t)8 * 256 * 4096;  // [8][512][256]

  unsigned short* ws = (unsigned short*)d_ws;
  unsigned short* Q  = ws;                // [8][4096][256]  16 MB
  unsigned short* QT = Q + 8388608;       // [8][256][4096]  16 MB
  unsigned short* K  = QT + 8388608;      // [8][512][256]    2 MB
  unsigned short* VT = K + 1048576;       // [8][256][512]    2 MB
  unsigned short* PT = VT + 1048576;      // [8][512][4096]  32 MB
  unsigned short* part = PT + 16777216;   // [8][8][512][256] bf16, 16 MB
  float* invl = (float*)(part + 8388608); // [8][4096] f32, 128 KB
  // total ws use: 85,065,728 bytes

  k_cast_transpose<<<dim3(128, 8, 8), 256, 0, stream>>>(Fs, QT, Q, 256, 4096);
  k_cast_transpose<<<dim3(8, 16, 8), 256, 0, stream>>>(Ft, K, VT, 512, 256);
  k_attn<<<dim3(512), 256, 0, stream>>>(Q, K, VT, QT, out0, PT, invl);
  k_ptq<<<dim3(512), 256, 0, stream>>>(PT, QT, invl, part);
  k_red<<<dim3(512), 256, 0, stream>>>(part, out1);
}

// Round 27
// 82.270 us; speedup vs baseline: 1.4522x; 1.4522x over previous
//
#include <hip/hip_runtime.h>
#include <hip/hip_bf16.h>
#include <stdint.h>

// B=8, C=256, H=W=64 (N=4096), T=512
// out0 = F_s + (softmax(Fs_t @ Ft^T / sqrt(T)) @ Ft) in [B][C][N] layout, fp32
// out1 = P^T @ Fs_t   [B][T][C] fp32

typedef __attribute__((ext_vector_type(8))) short short8v;   // 8 bf16
typedef __attribute__((ext_vector_type(4))) float float4v;

#define MFMA16(a, b, c) __builtin_amdgcn_mfma_f32_16x16x32_bf16(a, b, c, 0, 0, 0)
#define SCALE 0.04419417382415922f  // 1/sqrt(512)

static __device__ __forceinline__ unsigned short f2bf(float f) {
  union { float f; uint32_t u; } v; v.f = f;
  uint32_t r = v.u + 0x7fffu + ((v.u >> 16) & 1u);   // RNE
  return (unsigned short)(r >> 16);
}
static __device__ __forceinline__ float bf2f(unsigned short u) {
  union { uint32_t u; float f; } v; v.u = (uint32_t)u << 16;
  return v.f;
}

// async global->LDS, 16B per lane; LDS dest is wave-uniform base + lane*16
static __device__ __forceinline__ void gload16(const void* g, void* l) {
  __builtin_amdgcn_global_load_lds(
      (const __attribute__((address_space(1))) void*)g,
      (__attribute__((address_space(3))) void*)l, 16, 0, 0);
}

// ---------- cast + transpose (unchanged) ----------
__global__ __launch_bounds__(256) void k_cast_transpose(
    const float* __restrict__ src, unsigned short* __restrict__ dstC,
    unsigned short* __restrict__ dstT, int R, int Cd) {
  __shared__ unsigned short tile[32][33];
  const size_t zoff = (size_t)blockIdx.z * R * Cd;
  const float* s = src + zoff;
  unsigned short* dc = dstC + zoff;
  unsigned short* dt = dstT + zoff;
  const int c0 = blockIdx.x * 32, r0 = blockIdx.y * 32;
  const int tid = threadIdx.x;
  const int r = tid >> 3, c4 = (tid & 7) * 4;

  float4 v = *(const float4*)&s[(size_t)(r0 + r) * Cd + c0 + c4];
  ushort4 bq;
  bq.x = f2bf(v.x); bq.y = f2bf(v.y); bq.z = f2bf(v.z); bq.w = f2bf(v.w);
  *(ushort4*)&dc[(size_t)(r0 + r) * Cd + c0 + c4] = bq;
  tile[r][c4 + 0] = bq.x; tile[r][c4 + 1] = bq.y;
  tile[r][c4 + 2] = bq.z; tile[r][c4 + 3] = bq.w;
  __syncthreads();
  ushort4 o;
  o.x = tile[c4 + 0][r]; o.y = tile[c4 + 1][r];
  o.z = tile[c4 + 2][r]; o.w = tile[c4 + 3][r];
  *(ushort4*)&dt[(size_t)(c0 + r) * R + r0 + c4] = o;
}

// ---------- k_attn v-stream (r27): r26 kernel, launch_bounds (256,2) ----------
// r26 post-mortem: (256,3) forced a 170-VGPR cap < transient peak-live
// (~190) -> allocator spilled (VGPR 84, +86 MB scratch WRITE). One-variable
// change: cap 256 (no spill). LDS 53,248 B still permits 3 blocks/CU, so if
// the allocator lands <=170 we get 12 waves/CU anyway; worst case 2 blocks
// (= r21-class occupancy with the same 32-barrier count).
__global__ __launch_bounds__(256, 2) void k_attn(
    const unsigned short* __restrict__ Qg, const unsigned short* __restrict__ Kg,
    const unsigned short* __restrict__ VTg, const unsigned short* __restrict__ QTg,
    float* __restrict__ out0, unsigned short* __restrict__ PTg,
    float* __restrict__ invlg) {
  __shared__ char smem[53248];

  const int tid = threadIdx.x;
  const int wave = tid >> 6, lane = tid & 63;
  const int l16 = lane & 15, lhi = lane >> 4;
  const int b = blockIdx.x & 7, nb = blockIdx.x >> 3;
  const int n0w = nb * 64 + wave * 16;       // this wave's 16 q-rows
  const int cx = (l16 & 7) << 4;             // swizzle for 512B rows (K)
  const int cx2 = (l16 & 3) << 4;            // swizzle for 64B rows (VT, Ps)

  const unsigned short* Qb = Qg + (size_t)b * 4096 * 256;
  const char* Kb = (const char*)(Kg + (size_t)b * 512 * 256);
  const char* VTb = (const char*)(VTg + (size_t)b * 256 * 512);
  char* Ps = smem + 49152 + wave * 1024;     // wave-private [16q][32t]

  // K chunk i = [32t][256c] 16 KB contiguous -> buf (2i)%3
#define STAGE_K(i_) do {                                                    \
    const char* src_ = Kb + (i_) * 16384;                                   \
    char* dst_ = smem + ((2 * (i_)) % 3) * 16384;                           \
    _Pragma("unroll")                                                       \
    for (int u = 0; u < 4; u++) {                                           \
      const int off = (tid + u * 256) * 16;                                 \
      gload16(src_ + (off ^ (((off >> 9) & 7) << 4)), dst_ + off);          \
    } } while (0)

  // VT chunk i = [256c][32t] 16 KB (64 B rows) -> buf (2i+1)%3
#define STAGE_V(i_) do {                                                    \
    char* dst_ = smem + ((2 * (i_) + 1) % 3) * 16384;                       \
    _Pragma("unroll")                                                       \
    for (int u = 0; u < 4; u++) {                                           \
      const int off = (tid + u * 256) * 16;                                 \
      const int r_ = off >> 6, ic_ = off & 63;                              \
      gload16(VTb + (size_t)r_ * 1024 + (i_) * 64 + (ic_ ^ ((r_ & 3) << 4)), \
              dst_ + off);                                                  \
    } } while (0)

  // ---- Q A-frags (rows = q = l16) ----
  short8v aQ[8];
#pragma unroll
  for (int kc = 0; kc < 8; kc++)
    aQ[kc] = *(const short8v*)(Qb + (size_t)(n0w + l16) * 256 + kc * 32 + lhi * 8);

  float4v oacc[16];
#pragma unroll
  for (int ct = 0; ct < 16; ct++) oacc[ct] = (float4v)0.f;
  float lrun[4] = {0.f, 0.f, 0.f, 0.f};

  unsigned short* PTb = PTg + (size_t)b * 512 * 4096;

  STAGE_K(0); STAGE_V(0);                    // 8 loads outstanding
#pragma unroll
  for (int i = 0; i < 16; i++) {
    // ---- even sub-iter (s=2i): K_i ready ----
    asm volatile("s_waitcnt vmcnt(4)" ::: "memory");   // K_i landed (mine)
    __builtin_amdgcn_s_barrier();                      // all waves' K_i landed
    if (i < 15) STAGE_K(i + 1);
    float4v s0 = (float4v)0.f, s1 = (float4v)0.f;
    {
      const char* kb = smem + ((2 * i) % 3) * 16384;
      const char* rb0 = kb + l16 * 512;                // t-tile 0 rows
      const char* rb1 = kb + (16 + l16) * 512;         // t-tile 1 rows
#pragma unroll
      for (int kc = 0; kc < 8; kc++) {
        short8v bf0 = *(const short8v*)(rb0 + ((kc * 64 + lhi * 16) ^ cx));
        s0 = MFMA16(aQ[kc], bf0, s0);
        short8v bf1 = *(const short8v*)(rb1 + ((kc * 64 + lhi * 16) ^ cx));
        s1 = MFMA16(aQ[kc], bf1, s1);
      }
    }
    asm volatile("s_waitcnt lgkmcnt(0)" ::: "memory");

    // ---- odd sub-iter (s=2i+1): V_i ready ----
    if (i < 15) asm volatile("s_waitcnt vmcnt(4)" ::: "memory");
    else        asm volatile("s_waitcnt vmcnt(0)" ::: "memory");
    __builtin_amdgcn_s_barrier();
    if (i < 15) STAGE_V(i + 1);
    // exp + l accumulate + Ps write (unnormalized E, bf16), wave-private
#pragma unroll
    for (int r = 0; r < 4; r++) {
      const int q = lhi * 4 + r;
      float p0 = __expf(s0[r] * SCALE);
      float p1 = __expf(s1[r] * SCALE);
      lrun[r] += p0 + p1;
      *(unsigned short*)(Ps + ((q * 64 + l16 * 2) ^ ((q & 3) << 4))) = f2bf(p0);
      *(unsigned short*)(Ps + ((q * 64 + (16 + l16) * 2) ^ ((q & 3) << 4))) = f2bf(p1);
    }
    asm volatile("s_waitcnt lgkmcnt(0)" ::: "memory");  // Ps visible (same wave)
    // PV: D[c][q] += VT_chunk @ E_chunk (K=32)
    {
      short8v pb = *(const short8v*)(Ps + ((l16 * 64 + lhi * 16) ^ cx2));
      const char* vb = smem + ((2 * i + 1) % 3) * 16384;
#pragma unroll
      for (int ct = 0; ct < 16; ct++) {
        const char* rb = vb + (ct * 16 + l16) * 64;    // row&3 == l16&3
        short8v av = *(const short8v*)(rb + ((lhi * 16) ^ cx2));
        oacc[ct] = MFMA16(av, pb, oacc[ct]);
      }
    }
    // PT write for chunk i (unnormalized): t2 = lane&31, q-cols half*8..+8
    {
      const int t2 = lane & 31, half = lane >> 5;
      unsigned short tmp[8];
#pragma unroll
      for (int j = 0; j < 8; j++) {
        const int q = half * 8 + j;
        tmp[j] = *(const unsigned short*)(Ps + ((q * 64 + t2 * 2) ^ ((q & 3) << 4)));
      }
      *(int4*)(PTb + (size_t)(32 * i + t2) * 4096 + n0w + half * 8) = *(int4*)tmp;
    }
    asm volatile("s_waitcnt lgkmcnt(0)" ::: "memory");
  }

  // ---- epilogue: l reduce -> invl; scale oacc; write out0 + invl ----
#pragma unroll
  for (int r = 0; r < 4; r++) {
    float l = lrun[r];
    l += __shfl_xor(l, 1); l += __shfl_xor(l, 2);
    l += __shfl_xor(l, 4); l += __shfl_xor(l, 8);
    lrun[r] = 1.0f / l;                      // invl for q = lhi*4 + r
  }
  // myinv for q = l16 (oacc col): gather via shfl from subgroup (l16>>2)
  const int srcl = (l16 >> 2) << 4;
  float va = __shfl(lrun[0], srcl), vb2 = __shfl(lrun[1], srcl);
  float vc = __shfl(lrun[2], srcl), vd = __shfl(lrun[3], srcl);
  const int rs = l16 & 3;
  float myinv = rs == 0 ? va : (rs == 1 ? vb2 : (rs == 2 ? vc : vd));
  if (lane < 16) invlg[(size_t)b * 4096 + n0w + lane] = myinv;

  const unsigned short* QTb = QTg + (size_t)b * 256 * 4096;
  float* o0 = out0 + (size_t)b * 256 * 4096;
#pragma unroll
  for (int ct = 0; ct < 16; ct++)
#pragma unroll
    for (int r = 0; r < 4; r++) {
      const int cgl = ct * 16 + lhi * 4 + r;
      const size_t off = (size_t)cgl * 4096 + n0w + l16;
      o0[off] = oacc[ct][r] * myinv + bf2f(QTb[off]);
    }
#undef STAGE_K
#undef STAGE_V
}

// ---------- k_ptq v8 (unchanged): split-K 8, bf16 partials, invl-scaled ----------
__global__ __launch_bounds__(256, 2) void k_ptq(
    const unsigned short* __restrict__ PTg, const unsigned short* __restrict__ QTg,
    const float* __restrict__ invlg, unsigned short* __restrict__ part) {
  __shared__ char smem[65536];

  const int tid = threadIdx.x;
  const int wave = tid >> 6, lane = tid & 63;
  const int l16 = lane & 15, lhi = lane >> 4;
  const int bid = blockIdx.x;
  const int t0 = (bid >> 6) * 64;
  const int grp = bid & 63;
  const int b = grp & 7, ksl = grp >> 3;
  const int cx = (l16 & 7) << 4;

  const unsigned short* PTrow =
      PTg + ((size_t)(b * 512 + t0 + wave * 16 + l16)) * 4096 + ksl * 512 + lhi * 8;
  const char* QTb = (const char*)(QTg + (size_t)b * 256 * 4096 + ksl * 512);
  const float* ivb = invlg + (size_t)b * 4096 + ksl * 512 + lhi * 8;

#define STAGE_Q(c_, buf_) do {                                              \
    _Pragma("unroll")                                                       \
    for (int u = 0; u < 8; u++) {                                           \
      const int off = (tid + u * 256) * 16;                                 \
      const int r_ = off >> 7, ic_ = off & 127;                             \
      gload16(QTb + (size_t)r_ * 8192 + (c_) * 128 + (ic_ ^ ((r_ & 7) << 4)), \
              smem + (buf_) * 32768 + off);                                 \
    } } while (0)

  float4v acc[16];
#pragma unroll
  for (int ct = 0; ct < 16; ct++) acc[ct] = (float4v)0.f;

  STAGE_Q(0, 0);
  __syncthreads();
#pragma unroll
  for (int c = 0; c < 8; c++) {
    const int buf = c & 1;
    short8v pa0 = *(const short8v*)(PTrow + c * 64);
    short8v pa1 = *(const short8v*)(PTrow + c * 64 + 32);
    // normalize A-frags by invl[n] (fp32 mul, repack bf16)
    {
      float4 iv0 = *(const float4*)(ivb + c * 64);
      float4 iv1 = *(const float4*)(ivb + c * 64 + 4);
      float4 iv2 = *(const float4*)(ivb + c * 64 + 32);
      float4 iv3 = *(const float4*)(ivb + c * 64 + 36);
      const float f0[8] = {iv0.x, iv0.y, iv0.z, iv0.w, iv1.x, iv1.y, iv1.z, iv1.w};
      const float f1[8] = {iv2.x, iv2.y, iv2.z, iv2.w, iv3.x, iv3.y, iv3.z, iv3.w};
#pragma unroll
      for (int j = 0; j < 8; j++) {
        pa0[j] = (short)f2bf(bf2f((unsigned short)pa0[j]) * f0[j]);
        pa1[j] = (short)f2bf(bf2f((unsigned short)pa1[j]) * f1[j]);
      }
    }
    if (c < 7) STAGE_Q(c + 1, buf ^ 1);
#pragma unroll
    for (int ct = 0; ct < 16; ct++) {
      const int row = ct * 16 + l16;             // row&7 == l16&7
      const char* rb = smem + buf * 32768 + row * 128;
      short8v b0 = *(const short8v*)(rb + ((lhi * 16) ^ cx));
      acc[ct] = MFMA16(pa0, b0, acc[ct]);
      short8v b1 = *(const short8v*)(rb + ((64 + lhi * 16) ^ cx));
      acc[ct] = MFMA16(pa1, b1, acc[ct]);
    }
    __syncthreads();
  }

  // partial[ksl][b][t][c] bf16 stores (l16 -> 16 contiguous c)
  unsigned short* pout = part + (((size_t)ksl * 8 + b) * 512 + t0 + wave * 16) * 256;
#pragma unroll
  for (int ct = 0; ct < 16; ct++)
#pragma unroll
    for (int r = 0; r < 4; r++)
      pout[(lhi * 4 + r) * 256 + ct * 16 + l16] = f2bf(acc[ct][r]);
#undef STAGE_Q
}

// ---------- k_red v3 (unchanged): out1 = sum over 8 bf16 partials ----------
__global__ __launch_bounds__(256) void k_red(
    const unsigned short* __restrict__ part, float* __restrict__ out1) {
  const size_t g = (size_t)(blockIdx.x * 256 + threadIdx.x) * 8;
  float s[8];
#pragma unroll
  for (int j = 0; j < 8; j++) s[j] = 0.f;
#pragma unroll
  for (int ksl = 0; ksl < 8; ksl++) {
    short8v v = *(const short8v*)(part + (size_t)ksl * 1048576 + g);
#pragma unroll
    for (int j = 0; j < 8; j++) s[j] += bf2f((unsigned short)v[j]);
  }
  float4 o0 = {s[0], s[1], s[2], s[3]};
  float4 o1 = {s[4], s[5], s[6], s[7]};
  *(float4*)(out1 + g) = o0;
  *(float4*)(out1 + g + 4) = o1;
}

extern "C" void kernel_launch(void* const* d_in, const int* in_sizes, int n_in,
                              void* d_out, int out_size, void* d_ws, size_t ws_size,
                              hipStream_t stream) {
  const float* Fs = (const float*)d_in[0];   // [8][256][4096]
  const float* Ft = (const float*)d_in[1];   // [8][512][256]
  float* out0 = (float*)d_out;               // [8][256][4096]
  float* out1 = out0 + (size_t)8 * 256 * 4096;  // [8][512][256]

  unsigned short* ws = (unsigned short*)d_ws;
  unsigned short* Q  = ws;                // [8][4096][256]  16 MB
  unsigned short* QT = Q + 8388608;       // [8][256][4096]  16 MB
  unsigned short* K  = QT + 8388608;      // [8][512][256]    2 MB
  unsigned short* VT = K + 1048576;       // [8][256][512]    2 MB
  unsigned short* PT = VT + 1048576;      // [8][512][4096]  32 MB
  unsigned short* part = PT + 16777216;   // [8][8][512][256] bf16, 16 MB
  float* invl = (float*)(part + 8388608); // [8][4096] f32, 128 KB
  // total ws use: 85,065,728 bytes

  k_cast_transpose<<<dim3(128, 8, 8), 256, 0, stream>>>(Fs, QT, Q, 256, 4096);
  k_cast_transpose<<<dim3(8, 16, 8), 256, 0, stream>>>(Ft, K, VT, 512, 256);
  k_attn<<<dim3(512), 256, 0, stream>>>(Q, K, VT, QT, out0, PT, invl);
  k_ptq<<<dim3(512), 256, 0, stream>>>(PT, QT, invl, part);
  k_red<<<dim3(512), 256, 0, stream>>>(part, out1);
}

// Round 28
// 76.158 us; speedup vs baseline: 1.5687x; 1.0803x over previous
//
#include <hip/hip_runtime.h>
#include <hip/hip_bf16.h>
#include <stdint.h>

// B=8, C=256, H=W=64 (N=4096), T=512
// out0 = F_s + (softmax(Fs_t @ Ft^T / sqrt(T)) @ Ft) in [B][C][N] layout, fp32
// out1 = P^T @ Fs_t   [B][T][C] fp32

typedef __attribute__((ext_vector_type(8))) short short8v;   // 8 bf16
typedef __attribute__((ext_vector_type(4))) float float4v;

#define MFMA16(a, b, c) __builtin_amdgcn_mfma_f32_16x16x32_bf16(a, b, c, 0, 0, 0)
#define SCALE 0.04419417382415922f  // 1/sqrt(512)

static __device__ __forceinline__ unsigned short f2bf(float f) {
  union { float f; uint32_t u; } v; v.f = f;
  uint32_t r = v.u + 0x7fffu + ((v.u >> 16) & 1u);   // RNE
  return (unsigned short)(r >> 16);
}
static __device__ __forceinline__ float bf2f(unsigned short u) {
  union { uint32_t u; float f; } v; v.u = (uint32_t)u << 16;
  return v.f;
}

// async global->LDS, 16B per lane; LDS dest is wave-uniform base + lane*16
static __device__ __forceinline__ void gload16(const void* g, void* l) {
  __builtin_amdgcn_global_load_lds(
      (const __attribute__((address_space(1))) void*)g,
      (__attribute__((address_space(3))) void*)l, 16, 0, 0);
}

// ---------- cast + transpose ----------
__global__ __launch_bounds__(256) void k_cast_transpose(
    const float* __restrict__ src, unsigned short* __restrict__ dstC,
    unsigned short* __restrict__ dstT, int R, int Cd) {
  __shared__ unsigned short tile[32][33];
  const size_t zoff = (size_t)blockIdx.z * R * Cd;
  const float* s = src + zoff;
  unsigned short* dc = dstC + zoff;
  unsigned short* dt = dstT + zoff;
  const int c0 = blockIdx.x * 32, r0 = blockIdx.y * 32;
  const int tid = threadIdx.x;
  const int r = tid >> 3, c4 = (tid & 7) * 4;

  float4 v = *(const float4*)&s[(size_t)(r0 + r) * Cd + c0 + c4];
  ushort4 bq;
  bq.x = f2bf(v.x); bq.y = f2bf(v.y); bq.z = f2bf(v.z); bq.w = f2bf(v.w);
  *(ushort4*)&dc[(size_t)(r0 + r) * Cd + c0 + c4] = bq;
  tile[r][c4 + 0] = bq.x; tile[r][c4 + 1] = bq.y;
  tile[r][c4 + 2] = bq.z; tile[r][c4 + 3] = bq.w;
  __syncthreads();
  ushort4 o;
  o.x = tile[c4 + 0][r]; o.y = tile[c4 + 1][r];
  o.z = tile[c4 + 2][r]; o.w = tile[c4 + 3][r];
  *(ushort4*)&dt[(size_t)(c0 + r) * R + r0 + c4] = o;
}

// ---------- k_attn (r25/r21 best — 42.1 us, third reproduction) ----------
// 2q x 2t wave split, 4x16KB stage buffers, 3-deep counted-vmcnt pipeline.
// Occupancy experiments falsified on all arms (r24/r26: forced-cap spill;
// r27: no spill but HW never schedules a 3rd block). This structure's
// plateau is 8 waves/CU; holding the measured best.
// LDS 81,920 B -> 2 blocks/CU.
__global__ __launch_bounds__(256, 2) void k_attn(
    const unsigned short* __restrict__ Qg, const unsigned short* __restrict__ Kg,
    const unsigned short* __restrict__ VTg, const unsigned short* __restrict__ QTg,
    float* __restrict__ out0, unsigned short* __restrict__ PTg) {
  __shared__ char smem[81920];

  const int tid = threadIdx.x;
  const int wave = tid >> 6, lane = tid & 63;
  const int l16 = lane & 15, lhi = lane >> 4;
  const int wq = wave >> 1, wt = wave & 1;
  const int b = blockIdx.x & 7, nb = blockIdx.x >> 3;
  const int n0 = nb * 64;
  const int cx = (l16 & 7) << 4;             // read swizzle

  const unsigned short* Qb = Qg + (size_t)b * 4096 * 256;
  const char* Kb = (const char*)(Kg + (size_t)b * 512 * 256);
  const char* VTb = (const char*)(VTg + (size_t)b * 256 * 512);

#define STAGE_K16(c_) do {                                                  \
    const char* src_ = Kb + (c_) * 16384;                                   \
    char* dst_ = smem + ((c_) & 3) * 16384;                                 \
    _Pragma("unroll")                                                       \
    for (int i = 0; i < 4; i++) {                                           \
      const int off = (tid + i * 256) * 16;                                 \
      gload16(src_ + (off ^ (((off >> 9) & 7) << 4)), dst_ + off);          \
    } } while (0)

#define STAGE_VT16(v_) do {                                                 \
    const int ch_ = (v_) & 1, tau_ = (v_) >> 1;                             \
    char* dst_ = smem + ((v_) & 3) * 16384;                                 \
    _Pragma("unroll")                                                       \
    for (int i = 0; i < 4; i++) {                                           \
      const int off = (tid + i * 256) * 16;                                 \
      const int r_ = off >> 7, ic_ = off & 127;                             \
      gload16(VTb + (size_t)(ch_ * 128 + r_) * 1024 + tau_ * 128            \
                  + (ic_ ^ ((r_ & 7) << 4)),                                \
              dst_ + off);                                                  \
    } } while (0)

#define PS_WRITE(tau_) do {                                                 \
    char* PsN = smem + 65536 + ((tau_) & 1) * 8192 + wq * 4096;             \
    _Pragma("unroll")                                                       \
    for (int qt = 0; qt < 2; qt++)                                          \
      _Pragma("unroll")                                                     \
      for (int cc = 0; cc < 2; cc++)                                        \
        _Pragma("unroll")                                                   \
        for (int r = 0; r < 4; r++) {                                       \
          const int q = qt * 16 + lhi * 4 + r;                              \
          const int t2 = cc * 32 + wt * 16 + l16;                           \
          const uint32_t w = pk[(qt * 16 + (tau_) * 2 + cc) * 2 + (r >> 1)];\
          *(unsigned short*)(PsN + ((q * 128 + t2 * 2) ^ ((q & 7) << 4))) = \
              (unsigned short)(w >> ((r & 1) * 16));                        \
        } } while (0)

  // ---- Q A-frags: 2 q-tiles (rows = q = wq*32 + qt*16 + l16) ----
  short8v aQ[2][8];
#pragma unroll
  for (int qt = 0; qt < 2; qt++)
#pragma unroll
    for (int kc = 0; kc < 8; kc++)
      aQ[qt][kc] = *(const short8v*)(Qb +
          (size_t)(n0 + wq * 32 + qt * 16 + l16) * 256 + kc * 32 + lhi * 8);

  float4v acc[2][16];
#pragma unroll
  for (int qt = 0; qt < 2; qt++)
#pragma unroll
    for (int c = 0; c < 16; c++) acc[qt][c] = (float4v)0.f;

  // ---- phase 1: S = Q @ K^T, 16 chunks, 3-deep pipeline ----
  STAGE_K16(0); STAGE_K16(1); STAGE_K16(2);
#pragma unroll
  for (int c = 0; c < 16; c++) {
    asm volatile("s_waitcnt vmcnt(8)" ::: "memory");
    __builtin_amdgcn_s_barrier();
    if (c < 13) STAGE_K16(c + 3);
    else        STAGE_VT16(c - 13);
    const char* rb = smem + (c & 3) * 16384 + (wt * 16 + l16) * 512;
#pragma unroll
    for (int kc = 0; kc < 8; kc++) {
      short8v bf = *(const short8v*)(rb + ((kc * 64 + lhi * 16) ^ cx));
      acc[0][c] = MFMA16(aQ[0][kc], bf, acc[0][c]);
      acc[1][c] = MFMA16(aQ[1][kc], bf, acc[1][c]);
    }
    asm volatile("s_waitcnt lgkmcnt(0)" ::: "memory");
  }

  // ---- softmax: in-wave reduce + cross-wave wt-pair combine via red ----
  float* red = (float*)(smem + 65536 + 8192);  // 512 f32, parity-1 area
  float mx[2][4];
#pragma unroll
  for (int qt = 0; qt < 2; qt++)
#pragma unroll
    for (int r = 0; r < 4; r++) {
      float m = acc[qt][0][r];
#pragma unroll
      for (int c = 1; c < 16; c++) m = fmaxf(m, acc[qt][c][r]);
      m = fmaxf(m, __shfl_xor(m, 1));
      m = fmaxf(m, __shfl_xor(m, 2));
      m = fmaxf(m, __shfl_xor(m, 4));
      m = fmaxf(m, __shfl_xor(m, 8));
      mx[qt][r] = m;
    }
  if (l16 == 0) {
#pragma unroll
    for (int qt = 0; qt < 2; qt++)
#pragma unroll
      for (int r = 0; r < 4; r++)
        red[(wq * 2 + wt) * 32 + qt * 16 + lhi * 4 + r] = mx[qt][r];
  }
  __builtin_amdgcn_s_barrier();
  asm volatile("s_waitcnt lgkmcnt(0)" ::: "memory");
#pragma unroll
  for (int qt = 0; qt < 2; qt++)
#pragma unroll
    for (int r = 0; r < 4; r++) {
      const int q = qt * 16 + lhi * 4 + r;
      mx[qt][r] = fmaxf(red[(wq * 2 + 0) * 32 + q], red[(wq * 2 + 1) * 32 + q]);
    }
  float sm[2][4];
#pragma unroll
  for (int qt = 0; qt < 2; qt++)
#pragma unroll
    for (int r = 0; r < 4; r++) {
      float s = 0.f;
#pragma unroll
      for (int c = 0; c < 16; c++) {
        float p = __expf((acc[qt][c][r] - mx[qt][r]) * SCALE);
        acc[qt][c][r] = p;
        s += p;
      }
      s += __shfl_xor(s, 1); s += __shfl_xor(s, 2);
      s += __shfl_xor(s, 4); s += __shfl_xor(s, 8);
      sm[qt][r] = s;
    }
  if (l16 == 0) {
#pragma unroll
    for (int qt = 0; qt < 2; qt++)
#pragma unroll
      for (int r = 0; r < 4; r++)
        red[128 + (wq * 2 + wt) * 32 + qt * 16 + lhi * 4 + r] = sm[qt][r];
  }
  __builtin_amdgcn_s_barrier();
  asm volatile("s_waitcnt lgkmcnt(0)" ::: "memory");
#pragma unroll
  for (int qt = 0; qt < 2; qt++)
#pragma unroll
    for (int r = 0; r < 4; r++) {
      const int q = qt * 16 + lhi * 4 + r;
      sm[qt][r] = 1.0f / (red[128 + (wq * 2 + 0) * 32 + q] +
                          red[128 + (wq * 2 + 1) * 32 + q]);
    }

  // ---- pack P into bf16 regs: pk[(qt*16+c)*2+h] ----
  uint32_t pk[64];
#pragma unroll
  for (int qt = 0; qt < 2; qt++)
#pragma unroll
    for (int c = 0; c < 16; c++)
#pragma unroll
      for (int h = 0; h < 2; h++)
        pk[(qt * 16 + c) * 2 + h] =
            (uint32_t)f2bf(acc[qt][c][2 * h] * sm[qt][2 * h]) |
            ((uint32_t)f2bf(acc[qt][c][2 * h + 1] * sm[qt][2 * h + 1]) << 16);

  PS_WRITE(0);

  // ---- phase 2: PV, 16 chunks (v = tau*2+ch), same pipeline ----
  float4v oacc[8][2];
#pragma unroll
  for (int ct = 0; ct < 8; ct++)
#pragma unroll
    for (int qt = 0; qt < 2; qt++) oacc[ct][qt] = (float4v)0.f;

  unsigned short* PTb = PTg + (size_t)b * 512 * 4096;

#pragma unroll
  for (int v = 0; v < 16; v++) {
    if (v <= 13)      asm volatile("s_waitcnt vmcnt(8)" ::: "memory");
    else if (v == 14) asm volatile("s_waitcnt vmcnt(4)" ::: "memory");
    else              asm volatile("s_waitcnt vmcnt(0)" ::: "memory");
    __builtin_amdgcn_s_barrier();
    if (v < 13) STAGE_VT16(v + 3);
    const int tau = v >> 1, ch = v & 1;
    char* PsT = smem + 65536 + (tau & 1) * 8192 + wq * 4096;
    if (ch == wt) {
      short8v pb00 = *(const short8v*)(PsT + (((0 * 16 + l16) * 128 + 0 * 64 + lhi * 16) ^ cx));
      short8v pb01 = *(const short8v*)(PsT + (((0 * 16 + l16) * 128 + 1 * 64 + lhi * 16) ^ cx));
      short8v pb10 = *(const short8v*)(PsT + (((1 * 16 + l16) * 128 + 0 * 64 + lhi * 16) ^ cx));
      short8v pb11 = *(const short8v*)(PsT + (((1 * 16 + l16) * 128 + 1 * 64 + lhi * 16) ^ cx));
      const char* bufp = smem + (v & 3) * 16384;
#pragma unroll
      for (int ct = 0; ct < 8; ct++) {
        const char* rb = bufp + (ct * 16 + l16) * 128;   // row&7 == l16&7
        short8v a0 = *(const short8v*)(rb + ((lhi * 16) ^ cx));
        oacc[ct][0] = MFMA16(a0, pb00, oacc[ct][0]);
        oacc[ct][1] = MFMA16(a0, pb10, oacc[ct][1]);
        short8v a1 = *(const short8v*)(rb + ((64 + lhi * 16) ^ cx));
        oacc[ct][0] = MFMA16(a1, pb01, oacc[ct][0]);
        oacc[ct][1] = MFMA16(a1, pb11, oacc[ct][1]);
      }
    }
    if (ch == 1) {
      if (tau < 7) {
        const int taun = tau + 1;
        PS_WRITE(taun);
      }
      {
        const int t2 = wt * 32 + (lane & 31);
        const int cg = (lane >> 5) * 16;
        unsigned short tmp[16];
#pragma unroll
        for (int j = 0; j < 16; j++) {
          const int q = cg + j;
          tmp[j] = *(const unsigned short*)(PsT + ((q * 128 + t2 * 2) ^ ((q & 7) << 4)));
        }
        unsigned short* dst = PTb + (size_t)(tau * 64 + t2) * 4096 + n0 + wq * 32 + cg;
        *(int4*)dst = *(int4*)&tmp[0];
        *(int4*)(dst + 8) = *(int4*)&tmp[8];
      }
    }
    asm volatile("s_waitcnt lgkmcnt(0)" ::: "memory");
  }

  // ---- epilogue: out0[b][c][n] = oacc + residual(QT bf16) ----
  const unsigned short* QTb = QTg + (size_t)b * 256 * 4096;
  float* o0 = out0 + (size_t)b * 256 * 4096;
#pragma unroll
  for (int ct = 0; ct < 8; ct++)
#pragma unroll
    for (int qt = 0; qt < 2; qt++)
#pragma unroll
      for (int r = 0; r < 4; r++) {
        const int cgl = wt * 128 + ct * 16 + lhi * 4 + r;
        const int n = n0 + wq * 32 + qt * 16 + l16;
        const size_t off = (size_t)cgl * 4096 + n;
        o0[off] = oacc[ct][qt][r] + bf2f(QTb[off]);
      }
#undef STAGE_K16
#undef STAGE_VT16
#undef PS_WRITE
}

// ---------- k_ptq v7: split-K 8, grid 512, bf16 partials ----------
__global__ __launch_bounds__(256, 2) void k_ptq(
    const unsigned short* __restrict__ PTg, const unsigned short* __restrict__ QTg,
    unsigned short* __restrict__ part) {
  __shared__ char smem[65536];

  const int tid = threadIdx.x;
  const int wave = tid >> 6, lane = tid & 63;
  const int l16 = lane & 15, lhi = lane >> 4;
  const int bid = blockIdx.x;
  const int t0 = (bid >> 6) * 64;
  const int grp = bid & 63;
  const int b = grp & 7, ksl = grp >> 3;
  const int cx = (l16 & 7) << 4;

  const unsigned short* PTrow =
      PTg + ((size_t)(b * 512 + t0 + wave * 16 + l16)) * 4096 + ksl * 512 + lhi * 8;
  const char* QTb = (const char*)(QTg + (size_t)b * 256 * 4096 + ksl * 512);

#define STAGE_Q(c_, buf_) do {                                              \
    _Pragma("unroll")                                                       \
    for (int i = 0; i < 8; i++) {                                           \
      const int off = (tid + i * 256) * 16;                                 \
      const int r_ = off >> 7, ic_ = off & 127;                             \
      gload16(QTb + (size_t)r_ * 8192 + (c_) * 128 + (ic_ ^ ((r_ & 7) << 4)), \
              smem + (buf_) * 32768 + off);                                 \
    } } while (0)

  float4v acc[16];
#pragma unroll
  for (int ct = 0; ct < 16; ct++) acc[ct] = (float4v)0.f;

  STAGE_Q(0, 0);
  __syncthreads();
#pragma unroll
  for (int c = 0; c < 8; c++) {
    const int buf = c & 1;
    short8v pa0 = *(const short8v*)(PTrow + c * 64);
    short8v pa1 = *(const short8v*)(PTrow + c * 64 + 32);
    if (c < 7) STAGE_Q(c + 1, buf ^ 1);
#pragma unroll
    for (int ct = 0; ct < 16; ct++) {
      const int row = ct * 16 + l16;             // row&7 == l16&7
      const char* rb = smem + buf * 32768 + row * 128;
      short8v b0 = *(const short8v*)(rb + ((lhi * 16) ^ cx));
      acc[ct] = MFMA16(pa0, b0, acc[ct]);
      short8v b1 = *(const short8v*)(rb + ((64 + lhi * 16) ^ cx));
      acc[ct] = MFMA16(pa1, b1, acc[ct]);
    }
    __syncthreads();
  }

  // partial[ksl][b][t][c] bf16 stores (l16 -> 16 contiguous c)
  unsigned short* pout = part + (((size_t)ksl * 8 + b) * 512 + t0 + wave * 16) * 256;
#pragma unroll
  for (int ct = 0; ct < 16; ct++)
#pragma unroll
    for (int r = 0; r < 4; r++)
      pout[(lhi * 4 + r) * 256 + ct * 16 + l16] = f2bf(acc[ct][r]);
#undef STAGE_Q
}

// ---------- k_red v3: out1 = sum over 8 bf16 partials ----------
__global__ __launch_bounds__(256) void k_red(
    const unsigned short* __restrict__ part, float* __restrict__ out1) {
  const size_t g = (size_t)(blockIdx.x * 256 + threadIdx.x) * 8;
  float s[8];
#pragma unroll
  for (int j = 0; j < 8; j++) s[j] = 0.f;
#pragma unroll
  for (int ksl = 0; ksl < 8; ksl++) {
    short8v v = *(const short8v*)(part + (size_t)ksl * 1048576 + g);
#pragma unroll
    for (int j = 0; j < 8; j++) s[j] += bf2f((unsigned short)v[j]);
  }
  float4 o0 = {s[0], s[1], s[2], s[3]};
  float4 o1 = {s[4], s[5], s[6], s[7]};
  *(float4*)(out1 + g) = o0;
  *(float4*)(out1 + g + 4) = o1;
}

extern "C" void kernel_launch(void* const* d_in, const int* in_sizes, int n_in,
                              void* d_out, int out_size, void* d_ws, size_t ws_size,
                              hipStream_t stream) {
  const float* Fs = (const float*)d_in[0];   // [8][256][4096]
  const float* Ft = (const float*)d_in[1];   // [8][512][256]
  float* out0 = (float*)d_out;               // [8][256][4096]
  float* out1 = out0 + (size_t)8 * 256 * 4096;  // [8][512][256]

  unsigned short* ws = (unsigned short*)d_ws;
  unsigned short* Q  = ws;                // [8][4096][256]  16 MB
  unsigned short* QT = Q + 8388608;       // [8][256][4096]  16 MB
  unsigned short* K  = QT + 8388608;      // [8][512][256]    2 MB
  unsigned short* VT = K + 1048576;       // [8][256][512]    2 MB
  unsigned short* PT = VT + 1048576;      // [8][512][4096]  32 MB
  unsigned short* part = PT + 16777216;   // [8][8][512][256] bf16, 16 MB
  // total ws use: 84,934,656 bytes

  k_cast_transpose<<<dim3(128, 8, 8), 256, 0, stream>>>(Fs, QT, Q, 256, 4096);
  k_cast_transpose<<<dim3(8, 16, 8), 256, 0, stream>>>(Ft, K, VT, 512, 256);
  k_attn<<<dim3(512), 256, 0, stream>>>(Q, K, VT, QT, out0, PT);
  k_ptq<<<dim3(512), 256, 0, stream>>>(PT, QT, part);
  k_red<<<dim3(512), 256, 0, stream>>>(part, out1);
}